// Round 16
// baseline (176.870 us; speedup 1.0000x reference)
//
#include <hip/hip_runtime.h>
#include <hip/hip_bf16.h>
#include <hip/hip_fp16.h>

typedef _Float16 f16x8 __attribute__((ext_vector_type(8)));
typedef _Float16 f16x4 __attribute__((ext_vector_type(4)));
typedef float    f32x4 __attribute__((ext_vector_type(4)));

#define EPSV 1e-5f

// ---------------- prep: W2 -> fragment-swizzled f16 (W2T), W3 -> f16,
//                  + BN2/BN3 fold constants (block 0) ----------------
// W2T element order: [ks 0..15][cg 0..15][lane 0..63][e 0..7] where
//   ch = cg*16 + (lane&15),  k = ks*32 + (lane>>4)*8 + e.
__global__ void prep_convert(const float* __restrict__ W2, const float* __restrict__ W3,
                             const float* __restrict__ b2, const float* __restrict__ g2,
                             const float* __restrict__ be2, const float* __restrict__ m2,
                             const float* __restrict__ v2,
                             const float* __restrict__ b3, const float* __restrict__ g3,
                             const float* __restrict__ be3, const float* __restrict__ m3,
                             const float* __restrict__ v3,
                             _Float16* __restrict__ W2T, _Float16* __restrict__ W3h,
                             float* __restrict__ sc2, float* __restrict__ sh2,
                             float* __restrict__ sc3, float* __restrict__ sh3) {
  int tid = blockIdx.x * 256 + threadIdx.x;   // 64 blocks x 256 = 16384
  if (blockIdx.x == 0) {
    int t = threadIdx.x;
    if (t < 256) { float s = g2[t] * rsqrtf(v2[t] + EPSV); sc2[t] = s; sh2[t] = be2[t] + (b2[t] - m2[t]) * s; }
    if (t < 64)  { float s = g3[t] * rsqrtf(v3[t] + EPSV); sc3[t] = s; sh3[t] = be3[t] + (b3[t] - m3[t]) * s; }
  }
  {
    int lane = tid & 63, cg = (tid >> 6) & 15, ks = tid >> 10;
    int ch = cg * 16 + (lane & 15);
    int k  = ks * 32 + (lane >> 4) * 8;
    const float* src = W2 + (size_t)ch * 512 + k;
    f16x8 v;
    #pragma unroll
    for (int e = 0; e < 8; ++e) v[e] = (_Float16)src[e];
    *(f16x8*)(W2T + (size_t)tid * 8) = v;
  }
  W3h[tid] = (_Float16)W3[tid];   // 64*256 = 16384 elements
}

// ---------------- prep: layer-1 factorization (BN1 fold inlined) ----------------
// Layout: Ap[b][i][o] (o contiguous, f16). h1 = relu(A'[i] + B'[j]) generated in-kernel.
// ROUND 15: c-loop unrolled x8 (8 loads in flight, 8 independent FMA chains);
// sc1/sh1 computed inline (4 scalar rsqrt per block) -> prep_consts launch deleted.
__global__ void prep_ab(const float* __restrict__ x, const float* __restrict__ W1,
                        const float* __restrict__ b1, const float* __restrict__ g1,
                        const float* __restrict__ be1, const float* __restrict__ m1,
                        const float* __restrict__ v1,
                        _Float16* __restrict__ Ap, _Float16* __restrict__ Bp) {
  int b  = blockIdx.x >> 7;
  int og = blockIdx.x & 127;   // group of 4 output channels
  int i  = threadIdx.x;        // point index, coalesced on x
  float accA[4] = {0.f, 0.f, 0.f, 0.f};
  float accB[4] = {0.f, 0.f, 0.f, 0.f};
  const float* xb  = x  + (size_t)b * 128 * 256 + i;
  const float* w1r = W1 + (size_t)og * 4 * 256;   // uniform per block -> s_loads
  #pragma unroll 8
  for (int c = 0; c < 128; ++c) {
    float xa = xb[c * 256];
    #pragma unroll
    for (int oo = 0; oo < 4; ++oo) {
      accA[oo] = fmaf(w1r[oo * 256 + c],       xa, accA[oo]);
      accB[oo] = fmaf(w1r[oo * 256 + 128 + c], xa, accB[oo]);
    }
  }
  f16x4 oa, ob;
  {
    int o0 = og * 4;
    #pragma unroll
    for (int oo = 0; oo < 4; ++oo) {
      float s = g1[o0 + oo] * rsqrtf(v1[o0 + oo] + EPSV);          // SGPR-uniform
      float h = be1[o0 + oo] + (b1[o0 + oo] - m1[o0 + oo]) * s;
      oa[oo] = (_Float16)(accA[oo] * s + h);
      ob[oo] = (_Float16)(accB[oo] * s);
    }
  }
  size_t base = ((size_t)(b * 256 + i) << 9) + og * 4;
  *(f16x4*)(Ap + base) = oa;
  *(f16x4*)(Bp + base) = ob;
}

// ---------------- main fused kernel (round-12 exact: best verified) ----------------
// grid: 8192 blocks = b(8) x it(32) x jt(32); block = 256 thr = 4 waves.
// Block tile = 64 points (8i x 8j) x 256 channels; wave w = chQ: 64 ch x 64 pts,
// acc[4][4] = 64 AGPR. af PING-PONG double-buffer (r12, verified 174->155).
// r13 (4 blocks/CU): null — HW stays at 3. r14 (intra-wave pipeline): regressed
// — compiler already schedules this loop near-optimally; VGPR must stay 64.
struct alignas(16) Smem {
  union {
    struct { _Float16 sA[8][552]; _Float16 sB[8][552]; } s2;   // 17664 B
    struct { _Float16 h2[64][264]; float part[4][64]; } e;     // 34816 B
  } u;
};  // 34816 B x 3 blocks = 104 KB <= 160 KB

__global__ __launch_bounds__(256, 3) void edge_main(
    const _Float16* __restrict__ Ap, const _Float16* __restrict__ Bp,
    const _Float16* __restrict__ W2T, const _Float16* __restrict__ W3h,
    const float* __restrict__ sc2, const float* __restrict__ sh2,
    const float* __restrict__ sc3, const float* __restrict__ sh3,
    const float* __restrict__ W4, const float* __restrict__ b4,
    float* __restrict__ out) {
  __shared__ Smem sm;
  const int blk = blockIdx.x;
  const int b  = blk >> 10;
  const int it = (blk >> 5) & 31;
  const int jt = blk & 31;
  const int i0 = it * 8, j0 = jt * 8;

  const int t    = threadIdx.x;
  const int w    = t >> 6;      // chQ: channel quarter [64w, +64)
  const int lane = t & 63;
  const int llo  = lane & 15;   // MFMA row/col within fragment
  const int lhi  = lane >> 4;   // MFMA k-group
  const int gj   = llo & 7;     // j-row of this lane's point column
  const int giOff= llo >> 3;    // i-row parity within nt pair

  // ---- stage A'(8 rows) / B'(8 rows) into LDS [row][k] f16, coalesced ----
  if (t < 128) {
    int r = t >> 4, c = (t & 15) * 32;
    const _Float16* src = Ap + ((size_t)(b * 256 + i0 + r) << 9) + c;
    #pragma unroll
    for (int s = 0; s < 4; ++s)
      *(f16x8*)&sm.u.s2.sA[r][c + s * 8] = *(const f16x8*)(src + s * 8);
  } else {
    int tt = t - 128;
    int r = tt >> 4, c = (tt & 15) * 32;
    const _Float16* src = Bp + ((size_t)(b * 256 + j0 + r) << 9) + c;
    #pragma unroll
    for (int s = 0; s < 4; ++s)
      *(f16x8*)&sm.u.s2.sB[r][c + s * 8] = *(const f16x8*)(src + s * 8);
  }

  const f32x4 vzero = {0.f, 0.f, 0.f, 0.f};
  f32x4 acc[4][4];
  #pragma unroll
  for (int mt = 0; mt < 4; ++mt)
    #pragma unroll
    for (int nt = 0; nt < 4; ++nt) acc[mt][nt] = vzero;

  const f16x8 z8 = {};
  // af frag mt of chunk ks lives at: w2base + ks*8192 + mt*512 (f16)
  const _Float16* w2base = W2T + w * 2048 + lane * 8;

#define LOAD_AF(dst, kk)                                                     \
  {                                                                          \
    const _Float16* _p = w2base + (kk) * 8192;                               \
    _Pragma("unroll")                                                        \
    for (int mt = 0; mt < 4; ++mt)                                           \
      dst[mt] = *(const f16x8*)(_p + mt * 512);                              \
  }

#define KSTEP(afv, kk)                                                       \
  {                                                                          \
    const int k0 = (kk) * 32 + lhi * 8;                                      \
    f16x8 bv = *(const f16x8*)&sm.u.s2.sB[gj][k0];                           \
    f16x8 bfr[4];                                                            \
    _Pragma("unroll")                                                        \
    for (int nt = 0; nt < 4; ++nt) {                                         \
      f16x8 av = *(const f16x8*)&sm.u.s2.sA[nt * 2 + giOff][k0];             \
      f16x8 sv = av + bv;                                                    \
      bfr[nt] = __builtin_elementwise_max(sv, z8);                           \
    }                                                                        \
    _Pragma("unroll")                                                        \
    for (int mt = 0; mt < 4; ++mt)                                           \
      _Pragma("unroll")                                                      \
      for (int nt = 0; nt < 4; ++nt)                                         \
        acc[mt][nt] = __builtin_amdgcn_mfma_f32_16x16x32_f16(                \
            afv[mt], bfr[nt], acc[mt][nt], 0, 0, 0);                         \
  }

  // prologue: af for chunk 0 (issues during staging-store latency)
  f16x8 afA[4], afB[4];
  LOAD_AF(afA, 0);

  __syncthreads();   // sA/sB staged; k-loop needs no further barriers

  // ---- layer 2 K-loop: 16 chunks of K=32, barrier-free, af ping-pong ----
  for (int ks = 0; ks < 16; ks += 2) {
    LOAD_AF(afB, ks + 1);          // in flight across KSTEP(afA)
    KSTEP(afA, ks);
    if (ks + 2 < 16) LOAD_AF(afA, ks + 2);
    KSTEP(afB, ks + 1);
  }
#undef LOAD_AF
#undef KSTEP

  __syncthreads();   // all waves done with sA/sB; union switches to h2

  // ---- epilogue (single pass): BN2 + ReLU -> h2 (64 pts x this wave's 64 ch) ----
  #pragma unroll
  for (int mt = 0; mt < 4; ++mt) {
    int ch = w * 64 + mt * 16 + lhi * 4;
    float4 s = *(const float4*)(sc2 + ch);
    float4 h = *(const float4*)(sh2 + ch);
    #pragma unroll
    for (int nt = 0; nt < 4; ++nt) {
      int pt = nt * 16 + llo;
      f32x4 a = acc[mt][nt];
      f16x4 hb;
      hb[0] = (_Float16)fmaxf(fmaf(a[0], s.x, h.x), 0.f);
      hb[1] = (_Float16)fmaxf(fmaf(a[1], s.y, h.y), 0.f);
      hb[2] = (_Float16)fmaxf(fmaf(a[2], s.z, h.z), 0.f);
      hb[3] = (_Float16)fmaxf(fmaf(a[3], s.w, h.w), 0.f);
      *(f16x4*)&sm.u.e.h2[pt][ch] = hb;
    }
  }
  __syncthreads();

  // ---- layer 3: wave w -> output channels [16w, 16w+16), all 64 pts ----
  {
    f32x4 acc3[4];
    #pragma unroll
    for (int nt = 0; nt < 4; ++nt) acc3[nt] = vzero;
    const _Float16* w3p = W3h + (size_t)(w * 16 + llo) * 256 + lhi * 8;
    #pragma unroll
    for (int k8 = 0; k8 < 8; ++k8) {
      f16x8 a3 = *(const f16x8*)(w3p + k8 * 32);
      #pragma unroll
      for (int nt = 0; nt < 4; ++nt) {
        f16x8 b3 = *(const f16x8*)&sm.u.e.h2[nt * 16 + llo][k8 * 32 + lhi * 8];
        acc3[nt] = __builtin_amdgcn_mfma_f32_16x16x32_f16(a3, b3, acc3[nt], 0, 0, 0);
      }
    }
    // BN3 + ReLU + W4 fold; reduce over lhi groups via shfl
    int ch3 = w * 16 + lhi * 4;
    float4 s  = *(const float4*)(sc3 + ch3);
    float4 h  = *(const float4*)(sh3 + ch3);
    float4 wv = *(const float4*)(W4 + ch3);
    #pragma unroll
    for (int nt = 0; nt < 4; ++nt) {
      float p = fmaxf(fmaf(acc3[nt][0], s.x, h.x), 0.f) * wv.x
              + fmaxf(fmaf(acc3[nt][1], s.y, h.y), 0.f) * wv.y
              + fmaxf(fmaf(acc3[nt][2], s.z, h.z), 0.f) * wv.z
              + fmaxf(fmaf(acc3[nt][3], s.w, h.w), 0.f) * wv.w;
      p += __shfl_xor(p, 16);
      p += __shfl_xor(p, 32);
      if (lane < 16) sm.u.e.part[w][nt * 16 + llo] = p;   // lhi==0 lanes
    }
  }
  __syncthreads();

  // ---- cross-wave sum + sigmoid + store ----
  if (t < 64) {
    float tot = sm.u.e.part[0][t] + sm.u.e.part[1][t] + sm.u.e.part[2][t]
              + sm.u.e.part[3][t] + b4[0];
    float sg = 1.f / (1.f + __expf(-tot));
    out[(size_t)b * 65536 + (size_t)(i0 + (t >> 3)) * 256 + (j0 + (t & 7))] = sg;
  }
}

// ---------------- launcher ----------------
extern "C" void kernel_launch(void* const* d_in, const int* in_sizes, int n_in,
                              void* d_out, int out_size, void* d_ws, size_t ws_size,
                              hipStream_t stream) {
  const float* x   = (const float*)d_in[0];
  const float* W1  = (const float*)d_in[1];
  const float* b1  = (const float*)d_in[2];
  const float* g1  = (const float*)d_in[3];
  const float* be1 = (const float*)d_in[4];
  const float* m1  = (const float*)d_in[5];
  const float* v1  = (const float*)d_in[6];
  const float* W2  = (const float*)d_in[7];
  const float* b2  = (const float*)d_in[8];
  const float* g2  = (const float*)d_in[9];
  const float* be2 = (const float*)d_in[10];
  const float* m2  = (const float*)d_in[11];
  const float* v2  = (const float*)d_in[12];
  const float* W3  = (const float*)d_in[13];
  const float* b3  = (const float*)d_in[14];
  const float* g3  = (const float*)d_in[15];
  const float* be3 = (const float*)d_in[16];
  const float* m3  = (const float*)d_in[17];
  const float* v3  = (const float*)d_in[18];
  const float* W4  = (const float*)d_in[19];
  const float* b4  = (const float*)d_in[20];

  // workspace layout (~4.6 MB total)
  _Float16* Ap = (_Float16*)d_ws;        // 8*256*512 f16, [b][i][o]
  _Float16* Bp = Ap + 1048576;           // [b][j][o]
  float* sc2 = (float*)(Bp + 1048576);   // 256
  float* sh2 = sc2 + 256;                // 256
  float* sc3 = sh2 + 256;                // 64
  float* sh3 = sc3 + 64;                 // 64
  _Float16* W2T = (_Float16*)(sh3 + 64); // 131072 f16, fragment-swizzled
  _Float16* W3h = W2T + 131072;          // 16384 f16

  prep_convert<<<64, 256, 0, stream>>>(W2, W3, b2, g2, be2, m2, v2,
                                       b3, g3, be3, m3, v3,
                                       W2T, W3h, sc2, sh2, sc3, sh3);
  prep_ab<<<1024, 256, 0, stream>>>(x, W1, b1, g1, be1, m1, v1, Ap, Bp);
  edge_main<<<8192, 256, 0, stream>>>(Ap, Bp, W2T, W3h, sc2, sh2, sc3, sh3, W4, b4, (float*)d_out);
}

// Round 17
// 168.913 us; speedup vs baseline: 1.0471x; 1.0471x over previous
//
#include <hip/hip_runtime.h>
#include <hip/hip_bf16.h>
#include <hip/hip_fp16.h>

typedef _Float16 f16x8 __attribute__((ext_vector_type(8)));
typedef _Float16 f16x4 __attribute__((ext_vector_type(4)));
typedef float    f32x4 __attribute__((ext_vector_type(4)));

#define EPSV 1e-5f

// ---------------- prep: W2 -> fragment-swizzled f16 (W2T), W3 -> f16,
//                  + BN2/BN3 fold constants (block 0) ----------------
// W2T element order: [ks 0..15][cg 0..15][lane 0..63][e 0..7] where
//   ch = cg*16 + (lane&15),  k = ks*32 + (lane>>4)*8 + e.
__global__ void prep_convert(const float* __restrict__ W2, const float* __restrict__ W3,
                             const float* __restrict__ b2, const float* __restrict__ g2,
                             const float* __restrict__ be2, const float* __restrict__ m2,
                             const float* __restrict__ v2,
                             const float* __restrict__ b3, const float* __restrict__ g3,
                             const float* __restrict__ be3, const float* __restrict__ m3,
                             const float* __restrict__ v3,
                             _Float16* __restrict__ W2T, _Float16* __restrict__ W3h,
                             float* __restrict__ sc2, float* __restrict__ sh2,
                             float* __restrict__ sc3, float* __restrict__ sh3) {
  int tid = blockIdx.x * 256 + threadIdx.x;   // 64 blocks x 256 = 16384
  if (blockIdx.x == 0) {
    int t = threadIdx.x;
    if (t < 256) { float s = g2[t] * rsqrtf(v2[t] + EPSV); sc2[t] = s; sh2[t] = be2[t] + (b2[t] - m2[t]) * s; }
    if (t < 64)  { float s = g3[t] * rsqrtf(v3[t] + EPSV); sc3[t] = s; sh3[t] = be3[t] + (b3[t] - m3[t]) * s; }
  }
  {
    int lane = tid & 63, cg = (tid >> 6) & 15, ks = tid >> 10;
    int ch = cg * 16 + (lane & 15);
    int k  = ks * 32 + (lane >> 4) * 8;
    const float* src = W2 + (size_t)ch * 512 + k;
    f16x8 v;
    #pragma unroll
    for (int e = 0; e < 8; ++e) v[e] = (_Float16)src[e];
    *(f16x8*)(W2T + (size_t)tid * 8) = v;
  }
  W3h[tid] = (_Float16)W3[tid];   // 64*256 = 16384 elements
}

// ---------------- prep: layer-1 factorization (BN1 fold inlined) ----------------
__global__ void prep_ab(const float* __restrict__ x, const float* __restrict__ W1,
                        const float* __restrict__ b1, const float* __restrict__ g1,
                        const float* __restrict__ be1, const float* __restrict__ m1,
                        const float* __restrict__ v1,
                        _Float16* __restrict__ Ap, _Float16* __restrict__ Bp) {
  int b  = blockIdx.x >> 7;
  int og = blockIdx.x & 127;   // group of 4 output channels
  int i  = threadIdx.x;        // point index, coalesced on x
  float accA[4] = {0.f, 0.f, 0.f, 0.f};
  float accB[4] = {0.f, 0.f, 0.f, 0.f};
  const float* xb  = x  + (size_t)b * 128 * 256 + i;
  const float* w1r = W1 + (size_t)og * 4 * 256;   // uniform per block -> s_loads
  #pragma unroll 8
  for (int c = 0; c < 128; ++c) {
    float xa = xb[c * 256];
    #pragma unroll
    for (int oo = 0; oo < 4; ++oo) {
      accA[oo] = fmaf(w1r[oo * 256 + c],       xa, accA[oo]);
      accB[oo] = fmaf(w1r[oo * 256 + 128 + c], xa, accB[oo]);
    }
  }
  f16x4 oa, ob;
  {
    int o0 = og * 4;
    #pragma unroll
    for (int oo = 0; oo < 4; ++oo) {
      float s = g1[o0 + oo] * rsqrtf(v1[o0 + oo] + EPSV);          // SGPR-uniform
      float h = be1[o0 + oo] + (b1[o0 + oo] - m1[o0 + oo]) * s;
      oa[oo] = (_Float16)(accA[oo] * s + h);
      ob[oo] = (_Float16)(accB[oo] * s);
    }
  }
  size_t base = ((size_t)(b * 256 + i) << 9) + og * 4;
  *(f16x4*)(Ap + base) = oa;
  *(f16x4*)(Bp + base) = ob;
}

// ---------------- main fused kernel ----------------
// grid: 4096 blocks = b(8) x it(16) x jt(32); block = 256 thr = 4 waves.
// Block tile = 128 points (16i x 8j) x 256 channels.
// ROUND 17: FAT WAVES on the r12 structure. Wave (chH = w&1, ptH = w>>1):
// 128 ch x 64 pts, acc[8][4] = 128 AGPR, 32 MFMA/chunk (620cy stretch).
// At 2 waves/SIMD one wave's whole non-MFMA chain (~250cy LDS+gen) hides
// under the co-wave's MFMA stretch -> duty-cycle ceiling ~100% (vs ~60% at
// 64ch waves). Barrier-free k-loop + W2T-direct af + ping-pong all kept.
// Side benefits: gen redundancy 4x->2x, W2 L2 traffic 2GB->1GB.
// Regs: 128 AGPR + ~105 arch ~= 233 <= 256 (launch_bounds(256,2)).
struct alignas(16) Smem {
  union {
    struct { _Float16 sA[16][552]; _Float16 sB[8][552]; } s2;  // 26496 B
    struct { _Float16 h2[64][264]; float part[4][64]; } e;     // 34816 B
  } u;
};  // 34816 B x 2 blocks = 70 KB <= 160 KB

__global__ __launch_bounds__(256, 2) void edge_main(
    const _Float16* __restrict__ Ap, const _Float16* __restrict__ Bp,
    const _Float16* __restrict__ W2T, const _Float16* __restrict__ W3h,
    const float* __restrict__ sc2, const float* __restrict__ sh2,
    const float* __restrict__ sc3, const float* __restrict__ sh3,
    const float* __restrict__ W4, const float* __restrict__ b4,
    float* __restrict__ out) {
  __shared__ Smem sm;
  const int blk = blockIdx.x;
  const int b  = blk >> 9;
  const int it = (blk >> 5) & 15;
  const int jt = blk & 31;
  const int i0 = it * 16, j0 = jt * 8;

  const int t    = threadIdx.x;
  const int w    = t >> 6;
  const int lane = t & 63;
  const int llo  = lane & 15;   // MFMA row/col within fragment
  const int lhi  = lane >> 4;   // MFMA k-group
  const int gj   = llo & 7;     // j-row of this lane's point column
  const int giOff= llo >> 3;    // i-row parity within nt pair
  const int chH  = w & 1;       // channel half [128*chH, +128)
  const int ptH  = w >> 1;      // i-half: i_local in [8*ptH, +8)
  const int aBase= ptH * 8;

  // ---- stage A'(16 rows) / B'(8 rows) into LDS [row][k] f16, coalesced ----
  {
    int ra = t >> 4, ca = (t & 15) * 32;
    const _Float16* src = Ap + ((size_t)(b * 256 + i0 + ra) << 9) + ca;
    #pragma unroll
    for (int s = 0; s < 4; ++s)
      *(f16x8*)&sm.u.s2.sA[ra][ca + s * 8] = *(const f16x8*)(src + s * 8);
    int rb = t >> 5, cb = (t & 31) * 16;
    const _Float16* srcb = Bp + ((size_t)(b * 256 + j0 + rb) << 9) + cb;
    #pragma unroll
    for (int s = 0; s < 2; ++s)
      *(f16x8*)&sm.u.s2.sB[rb][cb + s * 8] = *(const f16x8*)(srcb + s * 8);
  }

  const f32x4 vzero = {0.f, 0.f, 0.f, 0.f};
  f32x4 acc[8][4];
  #pragma unroll
  for (int mt = 0; mt < 8; ++mt)
    #pragma unroll
    for (int nt = 0; nt < 4; ++nt) acc[mt][nt] = vzero;

  const f16x8 z8 = {};
  // af frag mt (mt 0..7, cg = chH*8+mt) of chunk ks: w2base + ks*8192 + mt*512
  const _Float16* w2base = W2T + chH * 4096 + lane * 8;

#define LOAD_AF(dst, kk)                                                     \
  {                                                                          \
    const _Float16* _p = w2base + (kk) * 8192;                               \
    _Pragma("unroll")                                                        \
    for (int mt = 0; mt < 8; ++mt)                                           \
      dst[mt] = *(const f16x8*)(_p + mt * 512);                              \
  }

#define KSTEP(afv, kk)                                                       \
  {                                                                          \
    const int k0 = (kk) * 32 + lhi * 8;                                      \
    f16x8 bv = *(const f16x8*)&sm.u.s2.sB[gj][k0];                           \
    f16x8 bfr[4];                                                            \
    _Pragma("unroll")                                                        \
    for (int nt = 0; nt < 4; ++nt) {                                         \
      f16x8 av = *(const f16x8*)&sm.u.s2.sA[aBase + nt * 2 + giOff][k0];     \
      f16x8 sv = av + bv;                                                    \
      bfr[nt] = __builtin_elementwise_max(sv, z8);                           \
    }                                                                        \
    _Pragma("unroll")                                                        \
    for (int mt = 0; mt < 8; ++mt)                                           \
      _Pragma("unroll")                                                      \
      for (int nt = 0; nt < 4; ++nt)                                         \
        acc[mt][nt] = __builtin_amdgcn_mfma_f32_16x16x32_f16(                \
            afv[mt], bfr[nt], acc[mt][nt], 0, 0, 0);                         \
  }

  // prologue: af for chunk 0 (issues during staging-store latency)
  f16x8 afA[8], afB[8];
  LOAD_AF(afA, 0);

  __syncthreads();   // sA/sB staged; k-loop needs no further barriers

  // ---- layer 2 K-loop: 16 chunks of K=32, barrier-free, af ping-pong ----
  for (int ks = 0; ks < 16; ks += 2) {
    LOAD_AF(afB, ks + 1);          // in flight across KSTEP(afA)
    KSTEP(afA, ks);
    if (ks + 2 < 16) LOAD_AF(afA, ks + 2);
    KSTEP(afB, ks + 1);
  }
#undef LOAD_AF
#undef KSTEP

  __syncthreads();   // all waves done with sA/sB; union switches to h2

  // ---- epilogue: 2 passes of 64 points ----
  #pragma unroll
  for (int pass = 0; pass < 2; ++pass) {
    // BN2 + ReLU -> h2: waves with ptH==pass write their 128 ch x 64 pts
    if (ptH == pass) {
      #pragma unroll
      for (int mt = 0; mt < 8; ++mt) {
        int ch = chH * 128 + mt * 16 + lhi * 4;
        float4 s = *(const float4*)(sc2 + ch);
        float4 h = *(const float4*)(sh2 + ch);
        #pragma unroll
        for (int nt = 0; nt < 4; ++nt) {
          int pt = nt * 16 + llo;
          f32x4 a = acc[mt][nt];
          f16x4 hb;
          hb[0] = (_Float16)fmaxf(fmaf(a[0], s.x, h.x), 0.f);
          hb[1] = (_Float16)fmaxf(fmaf(a[1], s.y, h.y), 0.f);
          hb[2] = (_Float16)fmaxf(fmaf(a[2], s.z, h.z), 0.f);
          hb[3] = (_Float16)fmaxf(fmaf(a[3], s.w, h.w), 0.f);
          *(f16x4*)&sm.u.e.h2[pt][ch] = hb;
        }
      }
    }
    __syncthreads();

    // layer 3: wave w -> output channels [16w, 16w+16), this pass's 64 pts
    {
      f32x4 acc3[4];
      #pragma unroll
      for (int nt = 0; nt < 4; ++nt) acc3[nt] = vzero;
      const _Float16* w3p = W3h + (size_t)(w * 16 + llo) * 256 + lhi * 8;
      #pragma unroll
      for (int k8 = 0; k8 < 8; ++k8) {
        f16x8 a3 = *(const f16x8*)(w3p + k8 * 32);
        #pragma unroll
        for (int nt = 0; nt < 4; ++nt) {
          f16x8 b3 = *(const f16x8*)&sm.u.e.h2[nt * 16 + llo][k8 * 32 + lhi * 8];
          acc3[nt] = __builtin_amdgcn_mfma_f32_16x16x32_f16(a3, b3, acc3[nt], 0, 0, 0);
        }
      }
      // BN3 + ReLU + W4 fold; reduce over lhi groups via shfl
      int ch3 = w * 16 + lhi * 4;
      float4 s  = *(const float4*)(sc3 + ch3);
      float4 h  = *(const float4*)(sh3 + ch3);
      float4 wv = *(const float4*)(W4 + ch3);
      #pragma unroll
      for (int nt = 0; nt < 4; ++nt) {
        float p = fmaxf(fmaf(acc3[nt][0], s.x, h.x), 0.f) * wv.x
                + fmaxf(fmaf(acc3[nt][1], s.y, h.y), 0.f) * wv.y
                + fmaxf(fmaf(acc3[nt][2], s.z, h.z), 0.f) * wv.z
                + fmaxf(fmaf(acc3[nt][3], s.w, h.w), 0.f) * wv.w;
        p += __shfl_xor(p, 16);
        p += __shfl_xor(p, 32);
        if (lane < 16) sm.u.e.part[w][nt * 16 + llo] = p;   // lhi==0 lanes
      }
    }
    __syncthreads();

    // cross-wave sum + sigmoid + store (this pass's 64 pts)
    if (t < 64) {
      float tot = sm.u.e.part[0][t] + sm.u.e.part[1][t] + sm.u.e.part[2][t]
                + sm.u.e.part[3][t] + b4[0];
      float sg = 1.f / (1.f + __expf(-tot));
      int il = pass * 8 + (t >> 3), jl = t & 7;
      out[(size_t)b * 65536 + (size_t)(i0 + il) * 256 + (j0 + jl)] = sg;
    }
    __syncthreads();   // part/h2 reads done before next pass reuses the union
  }
}

// ---------------- launcher ----------------
extern "C" void kernel_launch(void* const* d_in, const int* in_sizes, int n_in,
                              void* d_out, int out_size, void* d_ws, size_t ws_size,
                              hipStream_t stream) {
  const float* x   = (const float*)d_in[0];
  const float* W1  = (const float*)d_in[1];
  const float* b1  = (const float*)d_in[2];
  const float* g1  = (const float*)d_in[3];
  const float* be1 = (const float*)d_in[4];
  const float* m1  = (const float*)d_in[5];
  const float* v1  = (const float*)d_in[6];
  const float* W2  = (const float*)d_in[7];
  const float* b2  = (const float*)d_in[8];
  const float* g2  = (const float*)d_in[9];
  const float* be2 = (const float*)d_in[10];
  const float* m2  = (const float*)d_in[11];
  const float* v2  = (const float*)d_in[12];
  const float* W3  = (const float*)d_in[13];
  const float* b3  = (const float*)d_in[14];
  const float* g3  = (const float*)d_in[15];
  const float* be3 = (const float*)d_in[16];
  const float* m3  = (const float*)d_in[17];
  const float* v3  = (const float*)d_in[18];
  const float* W4  = (const float*)d_in[19];
  const float* b4  = (const float*)d_in[20];

  // workspace layout (~4.6 MB total)
  _Float16* Ap = (_Float16*)d_ws;        // 8*256*512 f16, [b][i][o]
  _Float16* Bp = Ap + 1048576;           // [b][j][o]
  float* sc2 = (float*)(Bp + 1048576);   // 256
  float* sh2 = sc2 + 256;                // 256
  float* sc3 = sh2 + 256;                // 64
  float* sh3 = sc3 + 64;                 // 64
  _Float16* W2T = (_Float16*)(sh3 + 64); // 131072 f16, fragment-swizzled
  _Float16* W3h = W2T + 131072;          // 16384 f16

  prep_convert<<<64, 256, 0, stream>>>(W2, W3, b2, g2, be2, m2, v2,
                                       b3, g3, be3, m3, v3,
                                       W2T, W3h, sc2, sh2, sc3, sh3);
  prep_ab<<<1024, 256, 0, stream>>>(x, W1, b1, g1, be1, m1, v1, Ap, Bp);
  edge_main<<<4096, 256, 0, stream>>>(Ap, Bp, W2T, W3h, sc2, sh2, sc3, sh3, W4, b4, (float*)d_out);
}

// Round 18
// 160.494 us; speedup vs baseline: 1.1020x; 1.0525x over previous
//
#include <hip/hip_runtime.h>
#include <hip/hip_bf16.h>
#include <hip/hip_fp16.h>

typedef _Float16 f16x8 __attribute__((ext_vector_type(8)));
typedef _Float16 f16x4 __attribute__((ext_vector_type(4)));
typedef float    f32x4 __attribute__((ext_vector_type(4)));

#define EPSV 1e-5f

// ---------------- prep: W2 -> stream-swizzled f16 (W2T), W3 -> f16,
//                  + BN2/BN3 fold constants (block 0) ----------------
// ROUND 18 layout: W2T[chH 0..1][ks 0..15][mt 0..7][lane 0..63][e 0..7] where
//   cg = chH*8+mt, ch = cg*16 + (lane&15), k = ks*32 + (lane>>4)*8 + e.
// A wave (chH) reads a CONTIGUOUS 8KB block per chunk -> linear 128KB stream.
__global__ void prep_convert(const float* __restrict__ W2, const float* __restrict__ W3,
                             const float* __restrict__ b2, const float* __restrict__ g2,
                             const float* __restrict__ be2, const float* __restrict__ m2,
                             const float* __restrict__ v2,
                             const float* __restrict__ b3, const float* __restrict__ g3,
                             const float* __restrict__ be3, const float* __restrict__ m3,
                             const float* __restrict__ v3,
                             _Float16* __restrict__ W2T, _Float16* __restrict__ W3h,
                             float* __restrict__ sc2, float* __restrict__ sh2,
                             float* __restrict__ sc3, float* __restrict__ sh3) {
  int tid = blockIdx.x * 256 + threadIdx.x;   // 64 blocks x 256 = 16384
  if (blockIdx.x == 0) {
    int t = threadIdx.x;
    if (t < 256) { float s = g2[t] * rsqrtf(v2[t] + EPSV); sc2[t] = s; sh2[t] = be2[t] + (b2[t] - m2[t]) * s; }
    if (t < 64)  { float s = g3[t] * rsqrtf(v3[t] + EPSV); sc3[t] = s; sh3[t] = be3[t] + (b3[t] - m3[t]) * s; }
  }
  {
    int lane = tid & 63;
    int mt   = (tid >> 6) & 7;
    int ks   = (tid >> 9) & 15;
    int chH  = (tid >> 13) & 1;
    int ch = (chH * 8 + mt) * 16 + (lane & 15);
    int k  = ks * 32 + (lane >> 4) * 8;
    const float* src = W2 + (size_t)ch * 512 + k;
    f16x8 v;
    #pragma unroll
    for (int e = 0; e < 8; ++e) v[e] = (_Float16)src[e];
    *(f16x8*)(W2T + (size_t)tid * 8) = v;
  }
  W3h[tid] = (_Float16)W3[tid];   // 64*256 = 16384 elements
}

// ---------------- prep: layer-1 factorization (BN1 fold inlined) ----------------
__global__ void prep_ab(const float* __restrict__ x, const float* __restrict__ W1,
                        const float* __restrict__ b1, const float* __restrict__ g1,
                        const float* __restrict__ be1, const float* __restrict__ m1,
                        const float* __restrict__ v1,
                        _Float16* __restrict__ Ap, _Float16* __restrict__ Bp) {
  int b  = blockIdx.x >> 7;
  int og = blockIdx.x & 127;   // group of 4 output channels
  int i  = threadIdx.x;        // point index, coalesced on x
  float accA[4] = {0.f, 0.f, 0.f, 0.f};
  float accB[4] = {0.f, 0.f, 0.f, 0.f};
  const float* xb  = x  + (size_t)b * 128 * 256 + i;
  const float* w1r = W1 + (size_t)og * 4 * 256;   // uniform per block -> s_loads
  #pragma unroll 8
  for (int c = 0; c < 128; ++c) {
    float xa = xb[c * 256];
    #pragma unroll
    for (int oo = 0; oo < 4; ++oo) {
      accA[oo] = fmaf(w1r[oo * 256 + c],       xa, accA[oo]);
      accB[oo] = fmaf(w1r[oo * 256 + 128 + c], xa, accB[oo]);
    }
  }
  f16x4 oa, ob;
  {
    int o0 = og * 4;
    #pragma unroll
    for (int oo = 0; oo < 4; ++oo) {
      float s = g1[o0 + oo] * rsqrtf(v1[o0 + oo] + EPSV);          // SGPR-uniform
      float h = be1[o0 + oo] + (b1[o0 + oo] - m1[o0 + oo]) * s;
      oa[oo] = (_Float16)(accA[oo] * s + h);
      ob[oo] = (_Float16)(accB[oo] * s);
    }
  }
  size_t base = ((size_t)(b * 256 + i) << 9) + og * 4;
  *(f16x4*)(Ap + base) = oa;
  *(f16x4*)(Bp + base) = ob;
}

// ---------------- main fused kernel ----------------
// grid: 4096 blocks = b(8) x it(16) x jt(32); block = 256 thr = 4 waves.
// Block tile = 128 points (16i x 8j) x 256 channels. Fat waves (r17, best total):
// wave (chH = w&1, ptH = w>>1): 128 ch x 64 pts, acc[8][4] = 128 AGPR,
// 32 MFMA/chunk; barrier-free k-loop, W2T-direct af, ping-pong prefetch.
// ROUND 18: (a) SINGLE-PASS epilogue — h2[128][264] (67.6KB) fits the union
// once the k-loop LDS is dead; all 4 waves BN2-write concurrently, L3 runs
// all 128 pts per wave (acc3[8]), 3 barriers instead of 6. (b) W2T stream
// layout: each wave's af marches linearly through 128KB (8KB/chunk contiguous).
struct alignas(16) Smem {
  union {
    struct { _Float16 sA[16][552]; _Float16 sB[8][552]; } s2;   // 26496 B
    struct { _Float16 h2[128][264]; float part[4][128]; } e;    // 69632 B
  } u;
};  // 69632 B x 2 blocks = 139 KB <= 160 KB

__global__ __launch_bounds__(256, 2) void edge_main(
    const _Float16* __restrict__ Ap, const _Float16* __restrict__ Bp,
    const _Float16* __restrict__ W2T, const _Float16* __restrict__ W3h,
    const float* __restrict__ sc2, const float* __restrict__ sh2,
    const float* __restrict__ sc3, const float* __restrict__ sh3,
    const float* __restrict__ W4, const float* __restrict__ b4,
    float* __restrict__ out) {
  __shared__ Smem sm;
  const int blk = blockIdx.x;
  const int b  = blk >> 9;
  const int it = (blk >> 5) & 15;
  const int jt = blk & 31;
  const int i0 = it * 16, j0 = jt * 8;

  const int t    = threadIdx.x;
  const int w    = t >> 6;
  const int lane = t & 63;
  const int llo  = lane & 15;   // MFMA row/col within fragment
  const int lhi  = lane >> 4;   // MFMA k-group
  const int gj   = llo & 7;     // j-row of this lane's point column
  const int giOff= llo >> 3;    // i-row parity within nt pair
  const int chH  = w & 1;       // channel half [128*chH, +128)
  const int ptH  = w >> 1;      // i-half: i_local in [8*ptH, +8)
  const int aBase= ptH * 8;

  // ---- stage A'(16 rows) / B'(8 rows) into LDS [row][k] f16, coalesced ----
  {
    int ra = t >> 4, ca = (t & 15) * 32;
    const _Float16* src = Ap + ((size_t)(b * 256 + i0 + ra) << 9) + ca;
    #pragma unroll
    for (int s = 0; s < 4; ++s)
      *(f16x8*)&sm.u.s2.sA[ra][ca + s * 8] = *(const f16x8*)(src + s * 8);
    int rb = t >> 5, cb = (t & 31) * 16;
    const _Float16* srcb = Bp + ((size_t)(b * 256 + j0 + rb) << 9) + cb;
    #pragma unroll
    for (int s = 0; s < 2; ++s)
      *(f16x8*)&sm.u.s2.sB[rb][cb + s * 8] = *(const f16x8*)(srcb + s * 8);
  }

  const f32x4 vzero = {0.f, 0.f, 0.f, 0.f};
  f32x4 acc[8][4];
  #pragma unroll
  for (int mt = 0; mt < 8; ++mt)
    #pragma unroll
    for (int nt = 0; nt < 4; ++nt) acc[mt][nt] = vzero;

  const f16x8 z8 = {};
  // af frag mt of chunk ks: w2base + ks*4096 + mt*512 (f16), linear stream
  const _Float16* w2base = W2T + chH * 65536 + lane * 8;

#define LOAD_AF(dst, kk)                                                     \
  {                                                                          \
    const _Float16* _p = w2base + (kk) * 4096;                               \
    _Pragma("unroll")                                                        \
    for (int mt = 0; mt < 8; ++mt)                                           \
      dst[mt] = *(const f16x8*)(_p + mt * 512);                              \
  }

#define KSTEP(afv, kk)                                                       \
  {                                                                          \
    const int k0 = (kk) * 32 + lhi * 8;                                      \
    f16x8 bv = *(const f16x8*)&sm.u.s2.sB[gj][k0];                           \
    f16x8 bfr[4];                                                            \
    _Pragma("unroll")                                                        \
    for (int nt = 0; nt < 4; ++nt) {                                         \
      f16x8 av = *(const f16x8*)&sm.u.s2.sA[aBase + nt * 2 + giOff][k0];     \
      f16x8 sv = av + bv;                                                    \
      bfr[nt] = __builtin_elementwise_max(sv, z8);                           \
    }                                                                        \
    _Pragma("unroll")                                                        \
    for (int mt = 0; mt < 8; ++mt)                                           \
      _Pragma("unroll")                                                      \
      for (int nt = 0; nt < 4; ++nt)                                         \
        acc[mt][nt] = __builtin_amdgcn_mfma_f32_16x16x32_f16(                \
            afv[mt], bfr[nt], acc[mt][nt], 0, 0, 0);                         \
  }

  // prologue: af for chunk 0 (issues during staging-store latency)
  f16x8 afA[8], afB[8];
  LOAD_AF(afA, 0);

  __syncthreads();   // sA/sB staged; k-loop needs no further barriers

  // ---- layer 2 K-loop: 16 chunks of K=32, barrier-free, af ping-pong ----
  for (int ks = 0; ks < 16; ks += 2) {
    LOAD_AF(afB, ks + 1);          // in flight across KSTEP(afA)
    KSTEP(afA, ks);
    if (ks + 2 < 16) LOAD_AF(afA, ks + 2);
    KSTEP(afB, ks + 1);
  }
#undef LOAD_AF
#undef KSTEP

  __syncthreads();   // all waves done with sA/sB; union switches to h2

  // ---- epilogue (SINGLE pass): BN2 + ReLU -> h2, all 4 waves concurrently ----
  #pragma unroll
  for (int mt = 0; mt < 8; ++mt) {
    int ch = chH * 128 + mt * 16 + lhi * 4;
    float4 s = *(const float4*)(sc2 + ch);
    float4 h = *(const float4*)(sh2 + ch);
    #pragma unroll
    for (int nt = 0; nt < 4; ++nt) {
      int pt = ptH * 64 + nt * 16 + llo;        // = i_local*8 + j
      f32x4 a = acc[mt][nt];
      f16x4 hb;
      hb[0] = (_Float16)fmaxf(fmaf(a[0], s.x, h.x), 0.f);
      hb[1] = (_Float16)fmaxf(fmaf(a[1], s.y, h.y), 0.f);
      hb[2] = (_Float16)fmaxf(fmaf(a[2], s.z, h.z), 0.f);
      hb[3] = (_Float16)fmaxf(fmaf(a[3], s.w, h.w), 0.f);
      *(f16x4*)&sm.u.e.h2[pt][ch] = hb;
    }
  }
  __syncthreads();

  // ---- layer 3: wave w -> output channels [16w, 16w+16), ALL 128 pts ----
  {
    f32x4 acc3[8];
    #pragma unroll
    for (int nt2 = 0; nt2 < 8; ++nt2) acc3[nt2] = vzero;
    const _Float16* w3p = W3h + (size_t)(w * 16 + llo) * 256 + lhi * 8;
    #pragma unroll
    for (int k8 = 0; k8 < 8; ++k8) {
      f16x8 a3 = *(const f16x8*)(w3p + k8 * 32);
      #pragma unroll
      for (int nt2 = 0; nt2 < 8; ++nt2) {
        f16x8 b3 = *(const f16x8*)&sm.u.e.h2[nt2 * 16 + llo][k8 * 32 + lhi * 8];
        acc3[nt2] = __builtin_amdgcn_mfma_f32_16x16x32_f16(a3, b3, acc3[nt2], 0, 0, 0);
      }
    }
    // BN3 + ReLU + W4 fold; reduce over lhi groups via shfl
    int ch3 = w * 16 + lhi * 4;
    float4 s  = *(const float4*)(sc3 + ch3);
    float4 h  = *(const float4*)(sh3 + ch3);
    float4 wv = *(const float4*)(W4 + ch3);
    #pragma unroll
    for (int nt2 = 0; nt2 < 8; ++nt2) {
      float p = fmaxf(fmaf(acc3[nt2][0], s.x, h.x), 0.f) * wv.x
              + fmaxf(fmaf(acc3[nt2][1], s.y, h.y), 0.f) * wv.y
              + fmaxf(fmaf(acc3[nt2][2], s.z, h.z), 0.f) * wv.z
              + fmaxf(fmaf(acc3[nt2][3], s.w, h.w), 0.f) * wv.w;
      p += __shfl_xor(p, 16);
      p += __shfl_xor(p, 32);
      if (lane < 16) sm.u.e.part[w][nt2 * 16 + llo] = p;   // lhi==0 lanes
    }
  }
  __syncthreads();

  // ---- cross-wave sum + sigmoid + store (all 128 pts) ----
  if (t < 128) {
    float tot = sm.u.e.part[0][t] + sm.u.e.part[1][t] + sm.u.e.part[2][t]
              + sm.u.e.part[3][t] + b4[0];
    float sg = 1.f / (1.f + __expf(-tot));
    out[(size_t)b * 65536 + (size_t)(i0 + (t >> 3)) * 256 + (j0 + (t & 7))] = sg;
  }
}

// ---------------- launcher ----------------
extern "C" void kernel_launch(void* const* d_in, const int* in_sizes, int n_in,
                              void* d_out, int out_size, void* d_ws, size_t ws_size,
                              hipStream_t stream) {
  const float* x   = (const float*)d_in[0];
  const float* W1  = (const float*)d_in[1];
  const float* b1  = (const float*)d_in[2];
  const float* g1  = (const float*)d_in[3];
  const float* be1 = (const float*)d_in[4];
  const float* m1  = (const float*)d_in[5];
  const float* v1  = (const float*)d_in[6];
  const float* W2  = (const float*)d_in[7];
  const float* b2  = (const float*)d_in[8];
  const float* g2  = (const float*)d_in[9];
  const float* be2 = (const float*)d_in[10];
  const float* m2  = (const float*)d_in[11];
  const float* v2  = (const float*)d_in[12];
  const float* W3  = (const float*)d_in[13];
  const float* b3  = (const float*)d_in[14];
  const float* g3  = (const float*)d_in[15];
  const float* be3 = (const float*)d_in[16];
  const float* m3  = (const float*)d_in[17];
  const float* v3  = (const float*)d_in[18];
  const float* W4  = (const float*)d_in[19];
  const float* b4  = (const float*)d_in[20];

  // workspace layout (~4.6 MB total)
  _Float16* Ap = (_Float16*)d_ws;        // 8*256*512 f16, [b][i][o]
  _Float16* Bp = Ap + 1048576;           // [b][j][o]
  float* sc2 = (float*)(Bp + 1048576);   // 256
  float* sh2 = sc2 + 256;                // 256
  float* sc3 = sh2 + 256;                // 64
  float* sh3 = sc3 + 64;                 // 64
  _Float16* W2T = (_Float16*)(sh3 + 64); // 131072 f16, stream-swizzled
  _Float16* W3h = W2T + 131072;          // 16384 f16

  prep_convert<<<64, 256, 0, stream>>>(W2, W3, b2, g2, be2, m2, v2,
                                       b3, g3, be3, m3, v3,
                                       W2T, W3h, sc2, sh2, sc3, sh3);
  prep_ab<<<1024, 256, 0, stream>>>(x, W1, b1, g1, be1, m1, v1, Ap, Bp);
  edge_main<<<4096, 256, 0, stream>>>(Ap, Bp, W2T, W3h, sc2, sh2, sc3, sh3, W4, b4, (float*)d_out);
}

// Round 19
// 159.739 us; speedup vs baseline: 1.1072x; 1.0047x over previous
//
#include <hip/hip_runtime.h>
#include <hip/hip_bf16.h>
#include <hip/hip_fp16.h>

typedef _Float16 f16x8 __attribute__((ext_vector_type(8)));
typedef _Float16 f16x4 __attribute__((ext_vector_type(4)));
typedef float    f32x4 __attribute__((ext_vector_type(4)));

#define EPSV 1e-5f

// ---------------- prep: W2 -> stream-swizzled f16 (W2T), W3 -> f16,
//                  + BN2/BN3 fold constants (block 0) ----------------
// W2T[chH 0..1][ks 0..15][mt 0..7][lane 0..63][e 0..7] where
//   cg = chH*8+mt, ch = cg*16 + (lane&15), k = ks*32 + (lane>>4)*8 + e.
// A wave (chH) reads a CONTIGUOUS 8KB block per chunk -> linear 128KB stream.
__global__ void prep_convert(const float* __restrict__ W2, const float* __restrict__ W3,
                             const float* __restrict__ b2, const float* __restrict__ g2,
                             const float* __restrict__ be2, const float* __restrict__ m2,
                             const float* __restrict__ v2,
                             const float* __restrict__ b3, const float* __restrict__ g3,
                             const float* __restrict__ be3, const float* __restrict__ m3,
                             const float* __restrict__ v3,
                             _Float16* __restrict__ W2T, _Float16* __restrict__ W3h,
                             float* __restrict__ sc2, float* __restrict__ sh2,
                             float* __restrict__ sc3, float* __restrict__ sh3) {
  int tid = blockIdx.x * 256 + threadIdx.x;   // 64 blocks x 256 = 16384
  if (blockIdx.x == 0) {
    int t = threadIdx.x;
    if (t < 256) { float s = g2[t] * rsqrtf(v2[t] + EPSV); sc2[t] = s; sh2[t] = be2[t] + (b2[t] - m2[t]) * s; }
    if (t < 64)  { float s = g3[t] * rsqrtf(v3[t] + EPSV); sc3[t] = s; sh3[t] = be3[t] + (b3[t] - m3[t]) * s; }
  }
  {
    int lane = tid & 63;
    int mt   = (tid >> 6) & 7;
    int ks   = (tid >> 9) & 15;
    int chH  = (tid >> 13) & 1;
    int ch = (chH * 8 + mt) * 16 + (lane & 15);
    int k  = ks * 32 + (lane >> 4) * 8;
    const float* src = W2 + (size_t)ch * 512 + k;
    f16x8 v;
    #pragma unroll
    for (int e = 0; e < 8; ++e) v[e] = (_Float16)src[e];
    *(f16x8*)(W2T + (size_t)tid * 8) = v;
  }
  W3h[tid] = (_Float16)W3[tid];   // 64*256 = 16384 elements
}

// ---------------- prep: layer-1 factorization (BN1 fold inlined) ----------------
__global__ void prep_ab(const float* __restrict__ x, const float* __restrict__ W1,
                        const float* __restrict__ b1, const float* __restrict__ g1,
                        const float* __restrict__ be1, const float* __restrict__ m1,
                        const float* __restrict__ v1,
                        _Float16* __restrict__ Ap, _Float16* __restrict__ Bp) {
  int b  = blockIdx.x >> 7;
  int og = blockIdx.x & 127;   // group of 4 output channels
  int i  = threadIdx.x;        // point index, coalesced on x
  float accA[4] = {0.f, 0.f, 0.f, 0.f};
  float accB[4] = {0.f, 0.f, 0.f, 0.f};
  const float* xb  = x  + (size_t)b * 128 * 256 + i;
  const float* w1r = W1 + (size_t)og * 4 * 256;   // uniform per block -> s_loads
  #pragma unroll 8
  for (int c = 0; c < 128; ++c) {
    float xa = xb[c * 256];
    #pragma unroll
    for (int oo = 0; oo < 4; ++oo) {
      accA[oo] = fmaf(w1r[oo * 256 + c],       xa, accA[oo]);
      accB[oo] = fmaf(w1r[oo * 256 + 128 + c], xa, accB[oo]);
    }
  }
  f16x4 oa, ob;
  {
    int o0 = og * 4;
    #pragma unroll
    for (int oo = 0; oo < 4; ++oo) {
      float s = g1[o0 + oo] * rsqrtf(v1[o0 + oo] + EPSV);          // SGPR-uniform
      float h = be1[o0 + oo] + (b1[o0 + oo] - m1[o0 + oo]) * s;
      oa[oo] = (_Float16)(accA[oo] * s + h);
      ob[oo] = (_Float16)(accB[oo] * s);
    }
  }
  size_t base = ((size_t)(b * 256 + i) << 9) + og * 4;
  *(f16x4*)(Ap + base) = oa;
  *(f16x4*)(Bp + base) = ob;
}

// ---------------- main fused kernel ----------------
// grid: 4096 blocks = b(8) x it(32) x jt(16); block = 256 thr = 4 waves.
// Block tile = 128 points (8i x 16j) x 256 channels. Fat waves (r17/r18 base):
// wave (chH = w&1, ptH = w>>1): 128 ch x 64 pts, acc[8][4] = 128 AGPR,
// 32 MFMA/chunk; barrier-free k-loop, W2T-direct af, ping-pong prefetch,
// single-pass epilogue (r18).
// ROUND 19: tile aspect SWAP 16ix8j -> 8ix16j. pt = i_local*16 + j, fragment
// nt <-> i_local = ptH*4+nt: av becomes a SINGLE-ROW broadcast (1 address,
// was 2), bv a 16-row strided read whose bank groups tile all 32 banks at the
// b128 floor. Also: afB(chunk 1) preloaded before the staging barrier (the
// barrier's vmcnt(0) drain makes it free) -> every af load now issues a full
// KSTEP (~620cy) ahead of use.
struct alignas(16) Smem {
  union {
    struct { _Float16 sA[8][552]; _Float16 sB[16][552]; } s2;   // 26496 B
    struct { _Float16 h2[128][264]; float part[4][128]; } e;    // 69632 B
  } u;
};  // 69632 B x 2 blocks = 139 KB <= 160 KB

__global__ __launch_bounds__(256, 2) void edge_main(
    const _Float16* __restrict__ Ap, const _Float16* __restrict__ Bp,
    const _Float16* __restrict__ W2T, const _Float16* __restrict__ W3h,
    const float* __restrict__ sc2, const float* __restrict__ sh2,
    const float* __restrict__ sc3, const float* __restrict__ sh3,
    const float* __restrict__ W4, const float* __restrict__ b4,
    float* __restrict__ out) {
  __shared__ Smem sm;
  const int blk = blockIdx.x;
  const int b  = blk >> 9;
  const int it = (blk >> 4) & 31;
  const int jt = blk & 15;
  const int i0 = it * 8, j0 = jt * 16;

  const int t    = threadIdx.x;
  const int w    = t >> 6;
  const int lane = t & 63;
  const int llo  = lane & 15;   // MFMA col within fragment == j (16 wide)
  const int lhi  = lane >> 4;   // MFMA k-group
  const int chH  = w & 1;       // channel half [128*chH, +128)
  const int ptH  = w >> 1;      // i-quarter: i_local in [4*ptH, +4)
  const int aBase= ptH * 4;

  // ---- stage A'(8 rows) / B'(16 rows) into LDS [row][k] f16, coalesced ----
  {
    int ra = t >> 5, ca = (t & 31) * 16;     // 8 rows, 32 thr/row, 16 f16/thr
    const _Float16* src = Ap + ((size_t)(b * 256 + i0 + ra) << 9) + ca;
    *(f16x8*)&sm.u.s2.sA[ra][ca]     = *(const f16x8*)(src);
    *(f16x8*)&sm.u.s2.sA[ra][ca + 8] = *(const f16x8*)(src + 8);
    int rb = t >> 4, cb = (t & 15) * 32;     // 16 rows, 16 thr/row, 32 f16/thr
    const _Float16* srcb = Bp + ((size_t)(b * 256 + j0 + rb) << 9) + cb;
    #pragma unroll
    for (int s = 0; s < 4; ++s)
      *(f16x8*)&sm.u.s2.sB[rb][cb + s * 8] = *(const f16x8*)(srcb + s * 8);
  }

  const f32x4 vzero = {0.f, 0.f, 0.f, 0.f};
  f32x4 acc[8][4];
  #pragma unroll
  for (int mt = 0; mt < 8; ++mt)
    #pragma unroll
    for (int nt = 0; nt < 4; ++nt) acc[mt][nt] = vzero;

  const f16x8 z8 = {};
  // af frag mt of chunk ks: w2base + ks*4096 + mt*512 (f16), linear stream
  const _Float16* w2base = W2T + chH * 65536 + lane * 8;

#define LOAD_AF(dst, kk)                                                     \
  {                                                                          \
    const _Float16* _p = w2base + (kk) * 4096;                               \
    _Pragma("unroll")                                                        \
    for (int mt = 0; mt < 8; ++mt)                                           \
      dst[mt] = *(const f16x8*)(_p + mt * 512);                              \
  }

#define KSTEP(afv, kk)                                                       \
  {                                                                          \
    const int k0 = (kk) * 32 + lhi * 8;                                      \
    f16x8 bv = *(const f16x8*)&sm.u.s2.sB[llo][k0];                          \
    f16x8 bfr[4];                                                            \
    _Pragma("unroll")                                                        \
    for (int nt = 0; nt < 4; ++nt) {                                         \
      f16x8 av = *(const f16x8*)&sm.u.s2.sA[aBase + nt][k0];                 \
      f16x8 sv = av + bv;                                                    \
      bfr[nt] = __builtin_elementwise_max(sv, z8);                           \
    }                                                                        \
    _Pragma("unroll")                                                        \
    for (int mt = 0; mt < 8; ++mt)                                           \
      _Pragma("unroll")                                                      \
      for (int nt = 0; nt < 4; ++nt)                                         \
        acc[mt][nt] = __builtin_amdgcn_mfma_f32_16x16x32_f16(                \
            afv[mt], bfr[nt], acc[mt][nt], 0, 0, 0);                         \
  }

  // prologue: af for chunks 0 AND 1 (the staging barrier drains vmcnt anyway)
  f16x8 afA[8], afB[8];
  LOAD_AF(afA, 0);
  LOAD_AF(afB, 1);

  __syncthreads();   // sA/sB staged; k-loop needs no further barriers

  // ---- layer 2 K-loop: 16 chunks of K=32, barrier-free, af ping-pong ----
  // every LOAD_AF is issued one full KSTEP (~620cy) before its KSTEP
  for (int ks = 0; ks < 16; ks += 2) {
    KSTEP(afA, ks);
    if (ks + 2 < 16) LOAD_AF(afA, ks + 2);
    KSTEP(afB, ks + 1);
    if (ks + 3 < 16) LOAD_AF(afB, ks + 3);
  }
#undef LOAD_AF
#undef KSTEP

  __syncthreads();   // all waves done with sA/sB; union switches to h2

  // ---- epilogue (single pass): BN2 + ReLU -> h2, all 4 waves concurrently ----
  #pragma unroll
  for (int mt = 0; mt < 8; ++mt) {
    int ch = chH * 128 + mt * 16 + lhi * 4;
    float4 s = *(const float4*)(sc2 + ch);
    float4 h = *(const float4*)(sh2 + ch);
    #pragma unroll
    for (int nt = 0; nt < 4; ++nt) {
      int pt = ptH * 64 + nt * 16 + llo;        // = i_local*16 + j
      f32x4 a = acc[mt][nt];
      f16x4 hb;
      hb[0] = (_Float16)fmaxf(fmaf(a[0], s.x, h.x), 0.f);
      hb[1] = (_Float16)fmaxf(fmaf(a[1], s.y, h.y), 0.f);
      hb[2] = (_Float16)fmaxf(fmaf(a[2], s.z, h.z), 0.f);
      hb[3] = (_Float16)fmaxf(fmaf(a[3], s.w, h.w), 0.f);
      *(f16x4*)&sm.u.e.h2[pt][ch] = hb;
    }
  }
  __syncthreads();

  // ---- layer 3: wave w -> output channels [16w, 16w+16), ALL 128 pts ----
  {
    f32x4 acc3[8];
    #pragma unroll
    for (int nt2 = 0; nt2 < 8; ++nt2) acc3[nt2] = vzero;
    const _Float16* w3p = W3h + (size_t)(w * 16 + llo) * 256 + lhi * 8;
    #pragma unroll
    for (int k8 = 0; k8 < 8; ++k8) {
      f16x8 a3 = *(const f16x8*)(w3p + k8 * 32);
      #pragma unroll
      for (int nt2 = 0; nt2 < 8; ++nt2) {
        f16x8 b3 = *(const f16x8*)&sm.u.e.h2[nt2 * 16 + llo][k8 * 32 + lhi * 8];
        acc3[nt2] = __builtin_amdgcn_mfma_f32_16x16x32_f16(a3, b3, acc3[nt2], 0, 0, 0);
      }
    }
    // BN3 + ReLU + W4 fold; reduce over lhi groups via shfl
    int ch3 = w * 16 + lhi * 4;
    float4 s  = *(const float4*)(sc3 + ch3);
    float4 h  = *(const float4*)(sh3 + ch3);
    float4 wv = *(const float4*)(W4 + ch3);
    #pragma unroll
    for (int nt2 = 0; nt2 < 8; ++nt2) {
      float p = fmaxf(fmaf(acc3[nt2][0], s.x, h.x), 0.f) * wv.x
              + fmaxf(fmaf(acc3[nt2][1], s.y, h.y), 0.f) * wv.y
              + fmaxf(fmaf(acc3[nt2][2], s.z, h.z), 0.f) * wv.z
              + fmaxf(fmaf(acc3[nt2][3], s.w, h.w), 0.f) * wv.w;
      p += __shfl_xor(p, 16);
      p += __shfl_xor(p, 32);
      if (lane < 16) sm.u.e.part[w][nt2 * 16 + llo] = p;   // lhi==0 lanes
    }
  }
  __syncthreads();

  // ---- cross-wave sum + sigmoid + store (all 128 pts; pt = i*16 + j) ----
  if (t < 128) {
    float tot = sm.u.e.part[0][t] + sm.u.e.part[1][t] + sm.u.e.part[2][t]
              + sm.u.e.part[3][t] + b4[0];
    float sg = 1.f / (1.f + __expf(-tot));
    out[(size_t)b * 65536 + (size_t)(i0 + (t >> 4)) * 256 + (j0 + (t & 15))] = sg;
  }
}

// ---------------- launcher ----------------
extern "C" void kernel_launch(void* const* d_in, const int* in_sizes, int n_in,
                              void* d_out, int out_size, void* d_ws, size_t ws_size,
                              hipStream_t stream) {
  const float* x   = (const float*)d_in[0];
  const float* W1  = (const float*)d_in[1];
  const float* b1  = (const float*)d_in[2];
  const float* g1  = (const float*)d_in[3];
  const float* be1 = (const float*)d_in[4];
  const float* m1  = (const float*)d_in[5];
  const float* v1  = (const float*)d_in[6];
  const float* W2  = (const float*)d_in[7];
  const float* b2  = (const float*)d_in[8];
  const float* g2  = (const float*)d_in[9];
  const float* be2 = (const float*)d_in[10];
  const float* m2  = (const float*)d_in[11];
  const float* v2  = (const float*)d_in[12];
  const float* W3  = (const float*)d_in[13];
  const float* b3  = (const float*)d_in[14];
  const float* g3  = (const float*)d_in[15];
  const float* be3 = (const float*)d_in[16];
  const float* m3  = (const float*)d_in[17];
  const float* v3  = (const float*)d_in[18];
  const float* W4  = (const float*)d_in[19];
  const float* b4  = (const float*)d_in[20];

  // workspace layout (~4.6 MB total)
  _Float16* Ap = (_Float16*)d_ws;        // 8*256*512 f16, [b][i][o]
  _Float16* Bp = Ap + 1048576;           // [b][j][o]
  float* sc2 = (float*)(Bp + 1048576);   // 256
  float* sh2 = sc2 + 256;                // 256
  float* sc3 = sh2 + 256;                // 64
  float* sh3 = sc3 + 64;                 // 64
  _Float16* W2T = (_Float16*)(sh3 + 64); // 131072 f16, stream-swizzled
  _Float16* W3h = W2T + 131072;          // 16384 f16

  prep_convert<<<64, 256, 0, stream>>>(W2, W3, b2, g2, be2, m2, v2,
                                       b3, g3, be3, m3, v3,
                                       W2T, W3h, sc2, sh2, sc3, sh3);
  prep_ab<<<1024, 256, 0, stream>>>(x, W1, b1, g1, be1, m1, v1, Ap, Bp);
  edge_main<<<4096, 256, 0, stream>>>(Ap, Bp, W2T, W3h, sc2, sh2, sc3, sh3, W4, b4, (float*)d_out);
}